// Round 8
// baseline (400.977 us; speedup 1.0000x reference)
//
#include <hip/hip_runtime.h>

// ---------------------------------------------------------------------------
// GCNConv (norm + linear + gather/scatter aggregate) + bias + PReLU
// N=100000 nodes, E=3200000 edges, IN_C=HID=128, all f32 in/out.
//
// R7: XCD-local histogram atomics. 8 per-XCD copies of hist; each block
// reads its physical XCD id (s_getreg HW_REG_XCC_ID) and updates copy x with
// a WORKGROUP-scope atomic (no sc1 -> RMW executes at the local XCD L2,
// hardware-atomic for the whole XCD; no cross-XCD coherence needed since
// copy x is only ever touched from XCD x). Kernel-boundary L2 writeback
// publishes results to later kernels.
//
// Encodings:
//  - hist[x*n+c]: u32 (count in bits[31:22], ew-sum fix15 in [21:0]); copy 0
//    initialized with the self-loop weight 1.0
//  - rank: u16 = within-(x,c) rank (12 bits) | x<<12
//  - xbase[c]: u64 = 8 x u8 exclusive prefix of per-XCD counts (deg < 256)
//  - csr:  packed u32 per edge  (src<<15 | fix14(dinv[src]*ew), src < 2^17)
//  - h:    bf16 (gather per edge 256B; h working set 25.6MB)
// ---------------------------------------------------------------------------

#define CNT_SHIFT 22
#define FIX15     32768.0f
#define FIX14     16384.0f
#define WSUM_MASK 0x3fffffu
#define SCAN_BS   512
#define NXCD      8

__device__ __forceinline__ unsigned xcc_id() {
    unsigned x;
    asm volatile("s_getreg_b32 %0, hwreg(HW_REG_XCC_ID)" : "=s"(x));
    return x & (NXCD - 1);
}

__device__ __forceinline__ unsigned bf16pack2(float a, float b) {
    unsigned ua = __float_as_uint(a);
    ua = (ua + 0x7fffu + ((ua >> 16) & 1u)) >> 16;   // RNE
    unsigned ub = __float_as_uint(b);
    ub = (ub + 0x7fffu + ((ub >> 16) & 1u)) >> 16;
    return ua | (ub << 16);
}

__device__ __forceinline__ float2 bf16unpack2(unsigned u) {
    return make_float2(__uint_as_float(u << 16),
                       __uint_as_float(u & 0xffff0000u));
}

__global__ void init_kernel(unsigned* __restrict__ hist, int n) {
    int i = blockIdx.x * blockDim.x + threadIdx.x;
    if (i < NXCD * n) hist[i] = (i < n) ? (unsigned)FIX15 : 0u;  // copy0: self-loop
}

__global__ void edge_count_kernel(const int* __restrict__ col,
                                  const float* __restrict__ ew,
                                  unsigned* __restrict__ hist,
                                  unsigned short* __restrict__ rank,
                                  int n, int e) {
    unsigned x = xcc_id();
    int i = blockIdx.x * blockDim.x + threadIdx.x;
    if (i < e) {
        int c = col[i];
        unsigned fx = (unsigned)(ew[i] * FIX15 + 0.5f);     // ew in [0,1)
        // XCD-local L2 atomic: copy x is only updated from XCD x.
        unsigned old = __hip_atomic_fetch_add(&hist[(size_t)x * n + c],
                                              (1u << CNT_SHIFT) | fx,
                                              __ATOMIC_RELAXED,
                                              __HIP_MEMORY_SCOPE_WORKGROUP);
        rank[i] = (unsigned short)(((old >> CNT_SHIFT) & 0xfffu) | (x << 12));
    }
}

// Phase 1: per-block sum of counts over the 8 copies (coalesced).
__global__ __launch_bounds__(SCAN_BS) void scan_partial_kernel(
    const unsigned* __restrict__ hist, int* __restrict__ partials, int n) {
    __shared__ int red[SCAN_BS];
    int t = threadIdx.x;
    int i = blockIdx.x * SCAN_BS + t;
    int s = 0;
    if (i < n) {
        #pragma unroll
        for (int x = 0; x < NXCD; ++x)
            s += (int)(hist[(size_t)x * n + i] >> CNT_SHIFT);
    }
    red[t] = s;
    __syncthreads();
    #pragma unroll
    for (int d = SCAN_BS / 2; d > 0; d >>= 1) {
        if (t < d) red[t] += red[t + d];
        __syncthreads();
    }
    if (t == 0) partials[blockIdx.x] = red[0];
}

// Phase 2: one block scans nb (<=1024) partials into exclusive bases, in place.
__global__ __launch_bounds__(1024) void scan_base_kernel(
    int* __restrict__ partials, int* __restrict__ offs, int nb, int n, int e) {
    __shared__ int s[1024];
    int t = threadIdx.x;
    int v = (t < nb) ? partials[t] : 0;
    s[t] = v;
    __syncthreads();
    for (int d = 1; d < 1024; d <<= 1) {
        int add = (t >= d) ? s[t - d] : 0;
        __syncthreads();
        s[t] += add;
        __syncthreads();
    }
    if (t < nb) partials[t] = s[t] - v;  // exclusive base
    if (t == 0) offs[n] = e;
}

// Phase 3: block scan + base -> offs; cross-XCD bases (xbase) + dinv fused.
__global__ __launch_bounds__(SCAN_BS) void scan_write_kernel(
    const unsigned* __restrict__ hist, const int* __restrict__ partials,
    int* __restrict__ offs, float* __restrict__ dinv,
    unsigned long long* __restrict__ xbase, int n) {
    __shared__ int s[SCAN_BS];
    int t = threadIdx.x;
    int i = blockIdx.x * SCAN_BS + t;
    int total = 0;
    unsigned wsum = 0;
    unsigned long long xb = 0;
    if (i < n) {
        unsigned run = 0;
        #pragma unroll
        for (int x = 0; x < NXCD; ++x) {
            unsigned hv = hist[(size_t)x * n + i];
            xb |= (unsigned long long)(run & 0xffu) << (8 * x);
            run += hv >> CNT_SHIFT;
            wsum += hv & WSUM_MASK;
        }
        total = (int)run;
    }
    s[t] = total;
    __syncthreads();
    for (int d = 1; d < SCAN_BS; d <<= 1) {
        int add = (t >= d) ? s[t - d] : 0;
        __syncthreads();
        s[t] += add;
        __syncthreads();
    }
    if (i < n) {
        offs[i] = partials[blockIdx.x] + s[t] - total;   // exclusive
        float dgr = (float)wsum * (1.0f / FIX15);
        dinv[i] = dgr > 0.0f ? rsqrtf(dgr) : 0.0f;       // >=1.0 (self-loop)
        xbase[i] = xb;
    }
}

__global__ void fill_kernel(const int* __restrict__ row, const int* __restrict__ col,
                            const float* __restrict__ ew, const float* __restrict__ dinv,
                            const unsigned short* __restrict__ rank,
                            const int* __restrict__ offs,
                            const unsigned long long* __restrict__ xbase,
                            unsigned* __restrict__ csr, int e) {
    int i = blockIdx.x * blockDim.x + threadIdx.x;
    if (i < e) {
        int r = row[i], c = col[i];
        float a = dinv[r] * ew[i];                    // a in [0,1]
        unsigned fa = (unsigned)(a * FIX14 + 0.5f);   // <= 16384 < 2^15
        unsigned rw = rank[i];
        unsigned x  = rw >> 12;
        unsigned rk = rw & 0xfffu;
        unsigned base = (unsigned)(xbase[c] >> (8 * x)) & 0xffu;
        int p = offs[c] + (int)base + (int)rk;
        csr[p] = ((unsigned)r << 15) | fa;
    }
}

// h = bf16(x @ W.T).  256 threads = 32 col-quads (tc) x 8 row-slots (rs); each
// thread computes 8 rows x 4 consecutive output channels (o = 4*tc + j).
// W^T staged in LDS as Wt[k][o], col XOR-swizzled by ((k&7)<<2) so the per-k
// float4 read across lanes (contiguous 512B) is bank-conflict-free.
__global__ __launch_bounds__(256) void gemm_kernel(const float* __restrict__ x,
                                                   const float* __restrict__ W,
                                                   unsigned* __restrict__ h, int n) {
    __shared__ float Wt[128][128];  // 64 KB
    int t = threadIdx.x;
    const float4* W4 = (const float4*)W;
    #pragma unroll
    for (int it = 0; it < 16; ++it) {
        int i = t + it * 256;        // float4 slot: o = i>>5 (W row), kq = i&31
        float4 v = W4[i];
        int o  = i >> 5;
        int kb = (i & 31) << 2;
        Wt[kb + 0][o ^ (((kb + 0) & 7) << 2)] = v.x;
        Wt[kb + 1][o ^ (((kb + 1) & 7) << 2)] = v.y;
        Wt[kb + 2][o ^ (((kb + 2) & 7) << 2)] = v.z;
        Wt[kb + 3][o ^ (((kb + 3) & 7) << 2)] = v.w;
    }
    __syncthreads();

    int tc = t & 31;
    int rs = t >> 5;
    int r0 = blockIdx.x * 64 + rs * 8;
    if (r0 >= n) return;            // after the sync: safe
    const float4* x4 = (const float4*)x;

    float acc[8][4];
    #pragma unroll
    for (int ri = 0; ri < 8; ++ri)
        #pragma unroll
        for (int j = 0; j < 4; ++j) acc[ri][j] = 0.0f;

    int rcnt = n - r0; if (rcnt > 8) rcnt = 8;

    if (rcnt == 8) {
        for (int kq = 0; kq < 32; ++kq) {
            int kb = kq << 2;
            float4 wv0 = *(const float4*)&Wt[kb + 0][(4 * tc) ^ (((kb + 0) & 7) << 2)];
            float4 wv1 = *(const float4*)&Wt[kb + 1][(4 * tc) ^ (((kb + 1) & 7) << 2)];
            float4 wv2 = *(const float4*)&Wt[kb + 2][(4 * tc) ^ (((kb + 2) & 7) << 2)];
            float4 wv3 = *(const float4*)&Wt[kb + 3][(4 * tc) ^ (((kb + 3) & 7) << 2)];
            #pragma unroll
            for (int ri = 0; ri < 8; ++ri) {
                float4 xv = x4[(size_t)(r0 + ri) * 32 + kq];
                acc[ri][0] += xv.x * wv0.x + xv.y * wv1.x + xv.z * wv2.x + xv.w * wv3.x;
                acc[ri][1] += xv.x * wv0.y + xv.y * wv1.y + xv.z * wv2.y + xv.w * wv3.y;
                acc[ri][2] += xv.x * wv0.z + xv.y * wv1.z + xv.z * wv2.z + xv.w * wv3.z;
                acc[ri][3] += xv.x * wv0.w + xv.y * wv1.w + xv.z * wv2.w + xv.w * wv3.w;
            }
        }
        uint2* h2 = (uint2*)h;
        #pragma unroll
        for (int ri = 0; ri < 8; ++ri)
            h2[(size_t)(r0 + ri) * 32 + tc] =
                make_uint2(bf16pack2(acc[ri][0], acc[ri][1]),
                           bf16pack2(acc[ri][2], acc[ri][3]));
    } else {
        for (int kq = 0; kq < 32; ++kq) {
            int kb = kq << 2;
            float4 wv0 = *(const float4*)&Wt[kb + 0][(4 * tc) ^ (((kb + 0) & 7) << 2)];
            float4 wv1 = *(const float4*)&Wt[kb + 1][(4 * tc) ^ (((kb + 1) & 7) << 2)];
            float4 wv2 = *(const float4*)&Wt[kb + 2][(4 * tc) ^ (((kb + 2) & 7) << 2)];
            float4 wv3 = *(const float4*)&Wt[kb + 3][(4 * tc) ^ (((kb + 3) & 7) << 2)];
            for (int ri = 0; ri < rcnt; ++ri) {
                float4 xv = x4[(size_t)(r0 + ri) * 32 + kq];
                acc[ri][0] += xv.x * wv0.x + xv.y * wv1.x + xv.z * wv2.x + xv.w * wv3.x;
                acc[ri][1] += xv.x * wv0.y + xv.y * wv1.y + xv.z * wv2.y + xv.w * wv3.y;
                acc[ri][2] += xv.x * wv0.z + xv.y * wv1.z + xv.z * wv2.z + xv.w * wv3.z;
                acc[ri][3] += xv.x * wv0.w + xv.y * wv1.w + xv.z * wv2.w + xv.w * wv3.w;
            }
        }
        uint2* h2 = (uint2*)h;
        for (int ri = 0; ri < rcnt; ++ri)
            h2[(size_t)(r0 + ri) * 32 + tc] =
                make_uint2(bf16pack2(acc[ri][0], acc[ri][1]),
                           bf16pack2(acc[ri][2], acc[ri][3]));
    }
}

// One 64-lane wave per node; each lane owns 2 channels (one bf16x2 u32).
// Per edge: one broadcast 4B csr word, gather 256B contiguous bf16 row of h.
__global__ __launch_bounds__(256) void aggregate_kernel(
    const unsigned* __restrict__ h, const unsigned* __restrict__ csr,
    const int* __restrict__ offs, const float* __restrict__ dinv,
    const float* __restrict__ bias, const float* __restrict__ alpha,
    float* __restrict__ out, int n) {
    int w = (blockIdx.x * 256 + threadIdx.x) >> 6;
    if (w >= n) return;
    int lane = threadIdx.x & 63;

    int beg = offs[w], end = offs[w + 1];
    float ax = 0.0f, ay = 0.0f;

    int i = beg;
    int end4 = beg + ((end - beg) & ~3);
    for (; i < end4; i += 4) {
        unsigned p0 = csr[i],     p1 = csr[i + 1];
        unsigned p2 = csr[i + 2], p3 = csr[i + 3];
        float a0 = (float)(p0 & 0x7fffu) * (1.0f / FIX14);
        float a1 = (float)(p1 & 0x7fffu) * (1.0f / FIX14);
        float a2 = (float)(p2 & 0x7fffu) * (1.0f / FIX14);
        float a3 = (float)(p3 & 0x7fffu) * (1.0f / FIX14);
        float2 v0 = bf16unpack2(h[(size_t)(p0 >> 15) * 64 + lane]);
        float2 v1 = bf16unpack2(h[(size_t)(p1 >> 15) * 64 + lane]);
        float2 v2 = bf16unpack2(h[(size_t)(p2 >> 15) * 64 + lane]);
        float2 v3 = bf16unpack2(h[(size_t)(p3 >> 15) * 64 + lane]);
        ax += a0 * v0.x; ay += a0 * v0.y;
        ax += a1 * v1.x; ay += a1 * v1.y;
        ax += a2 * v2.x; ay += a2 * v2.y;
        ax += a3 * v3.x; ay += a3 * v3.y;
    }
    for (; i < end; ++i) {
        unsigned p = csr[i];
        float a = (float)(p & 0x7fffu) * (1.0f / FIX14);
        float2 v = bf16unpack2(h[(size_t)(p >> 15) * 64 + lane]);
        ax += a * v.x; ay += a * v.y;
    }

    float dc = dinv[w];
    float2 hc = bf16unpack2(h[(size_t)w * 64 + lane]);  // self: dinv^2 * h[c]
    ax += dc * hc.x; ay += dc * hc.y;

    float2 bv = ((const float2*)bias)[lane];
    float2 av = ((const float2*)alpha)[lane];
    float ox = ax * dc + bv.x;
    float oy = ay * dc + bv.y;
    ox = ox > 0.0f ? ox : av.x * ox;
    oy = oy > 0.0f ? oy : av.y * oy;
    ((float2*)out)[(size_t)w * 64 + lane] = make_float2(ox, oy);
}

extern "C" void kernel_launch(void* const* d_in, const int* in_sizes, int n_in,
                              void* d_out, int out_size, void* d_ws, size_t ws_size,
                              hipStream_t stream) {
    const float* x     = (const float*)d_in[0];
    const int*   ei    = (const int*)d_in[1];
    const float* ew    = (const float*)d_in[2];
    const float* W     = (const float*)d_in[3];
    const float* bias  = (const float*)d_in[4];
    const float* alpha = (const float*)d_in[5];
    float* out = (float*)d_out;

    const int n = in_sizes[0] / 128;   // 100000
    const int e = in_sizes[1] / 2;     // 3200000
    const int* row = ei;               // edge_index[0] = source (gather)
    const int* col = ei + e;           // edge_index[1] = target (scatter)

    // workspace carve-out (256B aligned): ~50 MB total
    char* ws = (char*)d_ws;
    size_t off = 0;
    auto alloc = [&](size_t bytes) -> char* {
        char* p = ws + off;
        off = (off + bytes + 255) & ~(size_t)255;
        return p;
    };
    unsigned*           hist     = (unsigned*)          alloc((size_t)NXCD * n * 4);
    float*              dinv     = (float*)             alloc((size_t)n * 4);
    int*                offs     = (int*)               alloc((size_t)(n + 1) * 4);
    int*                partials = (int*)               alloc((size_t)1024 * 4);
    unsigned long long* xbase    = (unsigned long long*)alloc((size_t)n * 8);
    unsigned short*     rank     = (unsigned short*)    alloc((size_t)e * 2);
    unsigned*           csr      = (unsigned*)          alloc((size_t)e * 4);
    unsigned*           h        = (unsigned*)          alloc((size_t)n * 128 * 2);
    (void)ws_size; (void)n_in; (void)out_size;

    int gn8 = (NXCD * n + 255) / 256;
    int ge  = (e + 255) / 256;
    int nb  = (n + SCAN_BS - 1) / SCAN_BS;   // 196 blocks, fits <= 1024

    init_kernel<<<gn8, 256, 0, stream>>>(hist, n);
    edge_count_kernel<<<ge, 256, 0, stream>>>(col, ew, hist, rank, n, e);
    scan_partial_kernel<<<nb, SCAN_BS, 0, stream>>>(hist, partials, n);
    scan_base_kernel<<<1, 1024, 0, stream>>>(partials, offs, nb, n, e);
    scan_write_kernel<<<nb, SCAN_BS, 0, stream>>>(hist, partials, offs, dinv, xbase, n);
    fill_kernel<<<ge, 256, 0, stream>>>(row, col, ew, dinv, rank, offs, xbase, csr, e);

    int gg = (n + 63) / 64;  // 64 rows per block
    gemm_kernel<<<gg, 256, 0, stream>>>(x, W, h, n);

    int ga = (n + 3) / 4;    // 4 waves (nodes) per 256-thread block
    aggregate_kernel<<<ga, 256, 0, stream>>>(h, csr, offs, dinv, bias, alpha, out, n);
}

// Round 9
// 295.543 us; speedup vs baseline: 1.3567x; 1.3567x over previous
//
#include <hip/hip_runtime.h>

// ---------------------------------------------------------------------------
// GCNConv (norm + linear + gather/scatter aggregate) + bias + PReLU
// N=100000 nodes, E=3200000 edges, IN_C=HID=128, all f32 in/out.
//
// R8: ZERO global atomics. R6/R7 showed per-edge returning-atomics are capped
// at ~26 G/s (124us) regardless of scope or address spreading. Replace
// edge_count+fill with a bucket counting-sort (bucket = col>>6, 64 nodes):
//   p1_hist:  512 blocks, LDS histogram -> hist[bucket][block]   (no atomics)
//   scan x3:  exclusive scan of the 800k (bucket,block) counts
//   p2_scatter: same edge->block mapping, LDS cursors -> write u64 payload
//               ((col&63)<<32 | src<<15 | q15(ew)) into reserved slot
//   p3_build: one block per bucket: LDS per-node count + fix15 ew-sum (deg),
//             local scan, re-scatter zone (16KB, L2-hot) -> csr/offs/dinv
// csr word = src<<15 | q15(ew); aggregate folds a = dinv[src]*q/32767
// (dinv = 400KB, L2-resident broadcast load).
// h stays bf16 (fp8 would breach the absmax threshold: est. ~0.03 > 0.022).
// ---------------------------------------------------------------------------

#define NBLK    512          // blocks for p1/p2 (same edge mapping)
#define MAXBKT  1600         // >= ceil(100000/64) = 1563
#define QSCALE  32767.0f

__device__ __forceinline__ unsigned bf16pack2(float a, float b) {
    unsigned ua = __float_as_uint(a);
    ua = (ua + 0x7fffu + ((ua >> 16) & 1u)) >> 16;   // RNE
    unsigned ub = __float_as_uint(b);
    ub = (ub + 0x7fffu + ((ub >> 16) & 1u)) >> 16;
    return ua | (ub << 16);
}

__device__ __forceinline__ float2 bf16unpack2(unsigned u) {
    return make_float2(__uint_as_float(u << 16),
                       __uint_as_float(u & 0xffff0000u));
}

// ---- pass 1: per-(bucket,block) counts via LDS ----------------------------
__global__ __launch_bounds__(256) void p1_hist(const int* __restrict__ col,
                                               unsigned* __restrict__ hist,
                                               int e, int nbkt, int epb) {
    __shared__ unsigned lh[MAXBKT];
    int b = blockIdx.x;
    for (int k = threadIdx.x; k < nbkt; k += 256) lh[k] = 0;
    __syncthreads();
    int s = b * epb, en = s + epb; if (en > e) en = e;
    for (int i = s + threadIdx.x; i < en; i += 256)
        atomicAdd(&lh[col[i] >> 6], 1u);           // LDS atomic
    __syncthreads();
    for (int k = threadIdx.x; k < nbkt; k += 256)
        hist[(size_t)k * NBLK + b] = lh[k];
}

// ---- generic 3-phase exclusive scan over m counts -------------------------
__global__ __launch_bounds__(1024) void scan_partial2(
    const unsigned* __restrict__ a, unsigned* __restrict__ part, int m) {
    __shared__ unsigned red[1024];
    int t = threadIdx.x, i = blockIdx.x * 1024 + t;
    red[t] = (i < m) ? a[i] : 0;
    __syncthreads();
    #pragma unroll
    for (int d = 512; d > 0; d >>= 1) {
        if (t < d) red[t] += red[t + d];
        __syncthreads();
    }
    if (t == 0) part[blockIdx.x] = red[0];
}

__global__ __launch_bounds__(1024) void scan_base2(
    unsigned* __restrict__ part, int nb, int* __restrict__ offs, int n, int e) {
    __shared__ unsigned s[1024];
    int t = threadIdx.x;
    unsigned v = (t < nb) ? part[t] : 0;
    s[t] = v;
    __syncthreads();
    for (int d = 1; d < 1024; d <<= 1) {
        unsigned add = (t >= d) ? s[t - d] : 0;
        __syncthreads();
        s[t] += add;
        __syncthreads();
    }
    if (t < nb) part[t] = s[t] - v;   // exclusive base per scan-block
    if (t == 0) offs[n] = e;
}

__global__ __launch_bounds__(1024) void scan_write2(
    unsigned* __restrict__ a, const unsigned* __restrict__ part, int m) {
    __shared__ unsigned s[1024];
    int t = threadIdx.x, i = blockIdx.x * 1024 + t;
    unsigned v = (i < m) ? a[i] : 0;
    s[t] = v;
    __syncthreads();
    for (int d = 1; d < 1024; d <<= 1) {
        unsigned add = (t >= d) ? s[t - d] : 0;
        __syncthreads();
        s[t] += add;
        __syncthreads();
    }
    if (i < m) a[i] = part[blockIdx.x] + s[t] - v;   // exclusive, in place
}

// ---- pass 2: scatter payloads into reserved (bucket,block) ranges ---------
__global__ __launch_bounds__(256) void p2_scatter(
    const int* __restrict__ col, const int* __restrict__ row,
    const float* __restrict__ ew, const unsigned* __restrict__ base,
    unsigned long long* __restrict__ pay, int e, int nbkt, int epb) {
    __shared__ unsigned lbase[MAXBKT];
    __shared__ unsigned lcur[MAXBKT];
    int b = blockIdx.x;
    for (int k = threadIdx.x; k < nbkt; k += 256) {
        lbase[k] = base[(size_t)k * NBLK + b];
        lcur[k] = 0;
    }
    __syncthreads();
    int s = b * epb, en = s + epb; if (en > e) en = e;
    for (int i = s + threadIdx.x; i < en; i += 256) {
        int c = col[i];
        int bk = c >> 6;
        unsigned q  = (unsigned)(ew[i] * QSCALE + 0.5f);     // <= 32767
        unsigned lo = ((unsigned)row[i] << 15) | q;          // src17 | q15
        unsigned rk = atomicAdd(&lcur[bk], 1u);              // LDS atomic
        pay[(size_t)lbase[bk] + rk] =
            ((unsigned long long)(unsigned)(c & 63) << 32) | lo;
    }
}

// ---- pass 3: per-bucket local counting sort -> csr/offs/dinv --------------
__global__ __launch_bounds__(256) void p3_build(
    const unsigned long long* __restrict__ pay,
    const unsigned* __restrict__ histBase,
    unsigned* __restrict__ csr, int* __restrict__ offs,
    float* __restrict__ dinv, int n, int nbkt, int e) {
    __shared__ unsigned cnt[64], wsum[64], lofs[64], cur[64];
    int bk = blockIdx.x;
    int zs = (int)histBase[(size_t)bk * NBLK];
    int ze = (bk + 1 < nbkt) ? (int)histBase[(size_t)(bk + 1) * NBLK] : e;
    int t = threadIdx.x;
    if (t < 64) { cnt[t] = 0; wsum[t] = 0; cur[t] = 0; }
    __syncthreads();
    for (int p = zs + t; p < ze; p += 256) {
        unsigned long long v = pay[p];
        int l = (int)(v >> 32) & 63;
        atomicAdd(&cnt[l], 1u);
        atomicAdd(&wsum[l], (unsigned)v & 0x7fffu);
    }
    __syncthreads();
    if (t == 0) {
        unsigned run = 0;
        for (int l = 0; l < 64; ++l) { lofs[l] = run; run += cnt[l]; }
    }
    __syncthreads();
    for (int p = zs + t; p < ze; p += 256) {         // zone is L2-hot (16KB)
        unsigned long long v = pay[p];
        int l = (int)(v >> 32) & 63;
        unsigned rk = atomicAdd(&cur[l], 1u);
        csr[zs + lofs[l] + rk] = (unsigned)v;        // src<<15 | q15
    }
    if (t < 64) {
        int node = bk * 64 + t;
        if (node < n) {
            offs[node] = zs + (int)lofs[t];
            float dg = 1.0f + (float)wsum[t] * (1.0f / QSCALE);  // self-loop
            dinv[node] = rsqrtf(dg);
        }
    }
}

// ---- h = bf16(x @ W.T): f32 vector FMA, W^T in LDS (XOR-swizzled) ---------
__global__ __launch_bounds__(256) void gemm_kernel(const float* __restrict__ x,
                                                   const float* __restrict__ W,
                                                   unsigned* __restrict__ h, int n) {
    __shared__ float Wt[128][128];  // 64 KB
    int t = threadIdx.x;
    const float4* W4 = (const float4*)W;
    #pragma unroll
    for (int it = 0; it < 16; ++it) {
        int i = t + it * 256;        // float4 slot: o = i>>5 (W row), kq = i&31
        float4 v = W4[i];
        int o  = i >> 5;
        int kb = (i & 31) << 2;
        Wt[kb + 0][o ^ (((kb + 0) & 7) << 2)] = v.x;
        Wt[kb + 1][o ^ (((kb + 1) & 7) << 2)] = v.y;
        Wt[kb + 2][o ^ (((kb + 2) & 7) << 2)] = v.z;
        Wt[kb + 3][o ^ (((kb + 3) & 7) << 2)] = v.w;
    }
    __syncthreads();

    int tc = t & 31;
    int rs = t >> 5;
    int r0 = blockIdx.x * 64 + rs * 8;
    if (r0 >= n) return;            // after the sync: safe
    const float4* x4 = (const float4*)x;

    float acc[8][4];
    #pragma unroll
    for (int ri = 0; ri < 8; ++ri)
        #pragma unroll
        for (int j = 0; j < 4; ++j) acc[ri][j] = 0.0f;

    int rcnt = n - r0; if (rcnt > 8) rcnt = 8;

    if (rcnt == 8) {
        for (int kq = 0; kq < 32; ++kq) {
            int kb = kq << 2;
            float4 wv0 = *(const float4*)&Wt[kb + 0][(4 * tc) ^ (((kb + 0) & 7) << 2)];
            float4 wv1 = *(const float4*)&Wt[kb + 1][(4 * tc) ^ (((kb + 1) & 7) << 2)];
            float4 wv2 = *(const float4*)&Wt[kb + 2][(4 * tc) ^ (((kb + 2) & 7) << 2)];
            float4 wv3 = *(const float4*)&Wt[kb + 3][(4 * tc) ^ (((kb + 3) & 7) << 2)];
            #pragma unroll
            for (int ri = 0; ri < 8; ++ri) {
                float4 xv = x4[(size_t)(r0 + ri) * 32 + kq];
                acc[ri][0] += xv.x * wv0.x + xv.y * wv1.x + xv.z * wv2.x + xv.w * wv3.x;
                acc[ri][1] += xv.x * wv0.y + xv.y * wv1.y + xv.z * wv2.y + xv.w * wv3.y;
                acc[ri][2] += xv.x * wv0.z + xv.y * wv1.z + xv.z * wv2.z + xv.w * wv3.z;
                acc[ri][3] += xv.x * wv0.w + xv.y * wv1.w + xv.z * wv2.w + xv.w * wv3.w;
            }
        }
        uint2* h2 = (uint2*)h;
        #pragma unroll
        for (int ri = 0; ri < 8; ++ri)
            h2[(size_t)(r0 + ri) * 32 + tc] =
                make_uint2(bf16pack2(acc[ri][0], acc[ri][1]),
                           bf16pack2(acc[ri][2], acc[ri][3]));
    } else {
        for (int kq = 0; kq < 32; ++kq) {
            int kb = kq << 2;
            float4 wv0 = *(const float4*)&Wt[kb + 0][(4 * tc) ^ (((kb + 0) & 7) << 2)];
            float4 wv1 = *(const float4*)&Wt[kb + 1][(4 * tc) ^ (((kb + 1) & 7) << 2)];
            float4 wv2 = *(const float4*)&Wt[kb + 2][(4 * tc) ^ (((kb + 2) & 7) << 2)];
            float4 wv3 = *(const float4*)&Wt[kb + 3][(4 * tc) ^ (((kb + 3) & 7) << 2)];
            for (int ri = 0; ri < rcnt; ++ri) {
                float4 xv = x4[(size_t)(r0 + ri) * 32 + kq];
                acc[ri][0] += xv.x * wv0.x + xv.y * wv1.x + xv.z * wv2.x + xv.w * wv3.x;
                acc[ri][1] += xv.x * wv0.y + xv.y * wv1.y + xv.z * wv2.y + xv.w * wv3.y;
                acc[ri][2] += xv.x * wv0.z + xv.y * wv1.z + xv.z * wv2.z + xv.w * wv3.z;
                acc[ri][3] += xv.x * wv0.w + xv.y * wv1.w + xv.z * wv2.w + xv.w * wv3.w;
            }
        }
        uint2* h2 = (uint2*)h;
        for (int ri = 0; ri < rcnt; ++ri)
            h2[(size_t)(r0 + ri) * 32 + tc] =
                make_uint2(bf16pack2(acc[ri][0], acc[ri][1]),
                           bf16pack2(acc[ri][2], acc[ri][3]));
    }
}

// ---- aggregate: one wave per node, lane owns 2 channels (bf16x2 u32) ------
__global__ __launch_bounds__(256) void aggregate_kernel(
    const unsigned* __restrict__ h, const unsigned* __restrict__ csr,
    const int* __restrict__ offs, const float* __restrict__ dinv,
    const float* __restrict__ bias, const float* __restrict__ alpha,
    float* __restrict__ out, int n) {
    int w = (blockIdx.x * 256 + threadIdx.x) >> 6;
    if (w >= n) return;
    int lane = threadIdx.x & 63;

    int beg = offs[w], end = offs[w + 1];
    float ax = 0.0f, ay = 0.0f;

    int i = beg;
    int end4 = beg + ((end - beg) & ~3);
    for (; i < end4; i += 4) {
        unsigned p0 = csr[i],     p1 = csr[i + 1];
        unsigned p2 = csr[i + 2], p3 = csr[i + 3];
        unsigned s0 = p0 >> 15, s1 = p1 >> 15, s2 = p2 >> 15, s3 = p3 >> 15;
        float d0 = dinv[s0], d1 = dinv[s1], d2 = dinv[s2], d3 = dinv[s3];
        float2 v0 = bf16unpack2(h[(size_t)s0 * 64 + lane]);
        float2 v1 = bf16unpack2(h[(size_t)s1 * 64 + lane]);
        float2 v2 = bf16unpack2(h[(size_t)s2 * 64 + lane]);
        float2 v3 = bf16unpack2(h[(size_t)s3 * 64 + lane]);
        float a0 = d0 * (float)(p0 & 0x7fffu) * (1.0f / QSCALE);
        float a1 = d1 * (float)(p1 & 0x7fffu) * (1.0f / QSCALE);
        float a2 = d2 * (float)(p2 & 0x7fffu) * (1.0f / QSCALE);
        float a3 = d3 * (float)(p3 & 0x7fffu) * (1.0f / QSCALE);
        ax += a0 * v0.x; ay += a0 * v0.y;
        ax += a1 * v1.x; ay += a1 * v1.y;
        ax += a2 * v2.x; ay += a2 * v2.y;
        ax += a3 * v3.x; ay += a3 * v3.y;
    }
    for (; i < end; ++i) {
        unsigned p = csr[i];
        unsigned s = p >> 15;
        float a = dinv[s] * (float)(p & 0x7fffu) * (1.0f / QSCALE);
        float2 v = bf16unpack2(h[(size_t)s * 64 + lane]);
        ax += a * v.x; ay += a * v.y;
    }

    float dc = dinv[w];
    float2 hc = bf16unpack2(h[(size_t)w * 64 + lane]);  // self: dinv^2 * h[c]
    ax += dc * hc.x; ay += dc * hc.y;

    float2 bv = ((const float2*)bias)[lane];
    float2 av = ((const float2*)alpha)[lane];
    float ox = ax * dc + bv.x;
    float oy = ay * dc + bv.y;
    ox = ox > 0.0f ? ox : av.x * ox;
    oy = oy > 0.0f ? oy : av.y * oy;
    ((float2*)out)[(size_t)w * 64 + lane] = make_float2(ox, oy);
}

extern "C" void kernel_launch(void* const* d_in, const int* in_sizes, int n_in,
                              void* d_out, int out_size, void* d_ws, size_t ws_size,
                              hipStream_t stream) {
    const float* x     = (const float*)d_in[0];
    const int*   ei    = (const int*)d_in[1];
    const float* ew    = (const float*)d_in[2];
    const float* W     = (const float*)d_in[3];
    const float* bias  = (const float*)d_in[4];
    const float* alpha = (const float*)d_in[5];
    float* out = (float*)d_out;

    const int n = in_sizes[0] / 128;   // 100000
    const int e = in_sizes[1] / 2;     // 3200000
    const int* row = ei;               // edge_index[0] = source (gather)
    const int* col = ei + e;           // edge_index[1] = target (scatter)

    const int nbkt = (n + 63) >> 6;            // 1563 buckets of 64 nodes
    const int m    = nbkt * NBLK;              // 800256 (bucket,block) counts
    const int epb  = (e + NBLK - 1) / NBLK;    // 6250 edges per p1/p2 block
    const int nb2  = (m + 1023) / 1024;        // 782 scan blocks (<=1024)

    // workspace carve-out (256B aligned): ~68 MB total
    char* ws = (char*)d_ws;
    size_t off = 0;
    auto alloc = [&](size_t bytes) -> char* {
        char* p = ws + off;
        off = (off + bytes + 255) & ~(size_t)255;
        return p;
    };
    unsigned*           hist = (unsigned*)          alloc((size_t)m * 4);
    unsigned*           part = (unsigned*)          alloc((size_t)1024 * 4);
    int*                offs = (int*)               alloc((size_t)(n + 1) * 4);
    float*              dinv = (float*)             alloc((size_t)n * 4);
    unsigned long long* pay  = (unsigned long long*)alloc((size_t)e * 8);
    unsigned*           csr  = (unsigned*)          alloc((size_t)e * 4);
    unsigned*           h    = (unsigned*)          alloc((size_t)n * 128 * 2);
    (void)ws_size; (void)n_in; (void)out_size;

    p1_hist<<<NBLK, 256, 0, stream>>>(col, hist, e, nbkt, epb);
    scan_partial2<<<nb2, 1024, 0, stream>>>(hist, part, m);
    scan_base2<<<1, 1024, 0, stream>>>(part, nb2, offs, n, e);
    scan_write2<<<nb2, 1024, 0, stream>>>(hist, part, m);
    p2_scatter<<<NBLK, 256, 0, stream>>>(col, row, ew, hist, pay, e, nbkt, epb);
    p3_build<<<nbkt, 256, 0, stream>>>(pay, hist, csr, offs, dinv, n, nbkt, e);

    int gg = (n + 63) / 64;  // 64 rows per block
    gemm_kernel<<<gg, 256, 0, stream>>>(x, W, h, n);

    int ga = (n + 3) / 4;    // 4 waves (nodes) per 256-thread block
    aggregate_kernel<<<ga, 256, 0, stream>>>(h, csr, offs, dinv, bias, alpha, out, n);
}